// Round 10
// baseline (8582.655 us; speedup 1.0000x reference)
//
#include <hip/hip_runtime.h>

typedef __attribute__((ext_vector_type(4))) float f32x4;
typedef __attribute__((ext_vector_type(8))) __bf16 bf16x8;
typedef __attribute__((ext_vector_type(4))) unsigned short u16x4;
typedef unsigned long long ull;

#define GPAD 40   // GEMM LDS row pad (ushorts)
#define KEEPF(x) asm volatile("" : "+v"(x))
#define PHYS(i) ((i) + (((i) >> 6) << 2))   // +4 words pad per 64 -> conflict-light b128 slices
#define HWREG_XCC_ID ((20) | (0 << 6) | ((4 - 1) << 11))   // s_getreg: id=20, offset=0, size=4

// ---------------- persistent scratch ----------------
// Tagged u64 words: (step_tag<<32)|f32 bits.
// FAST path (intra-XCD): plain store -> XCD L2; sc0 (SE-scope) load reads that L2.
// SLOW path (cross-XCD, fallback): agent-scope relaxed atomics (L3/HBM-coherent).
// Every fast poll periodically checks the slow copy => wrong XCD placement or wrong
// sc0 semantics degrade performance but never correctness/progress.
__device__ ull g_h1f[1024], g_rh1f[1024], g_rh1R[1024];
__device__ ull g_h2f[1024], g_h2R[1024], g_rh2f[1024], g_rh2R[1024];
__device__ ull g_h1s[1025 * 1024];                      // L1 ring (slow): slot t = h1 after t steps, tag t
__device__ ull g_x2z[1025 * 1024];                      // proj->L2 rings (slow): slot s+1 tag s+1
__device__ ull g_x2r[1025 * 1024];
__device__ ull g_x2w[1025 * 1024];
__device__ int g_claim[4];
__device__ float g_ExW[1024 * 3072];                    // [step][z|r|w] layer-1 input terms
__device__ float g_hs2[1024 * 1024];

__device__ __forceinline__ unsigned short f2bf(float x) {
  unsigned u = __builtin_bit_cast(unsigned, x);
  u += 0x7FFFu + ((u >> 16) & 1u);   // RNE
  return (unsigned short)(u >> 16);
}
__device__ __forceinline__ ull packtv(unsigned tag, float v) {
  return ((ull)tag << 32) | (ull)__builtin_bit_cast(unsigned, v);
}
__device__ __forceinline__ ull aload(const ull* p) {
  return __hip_atomic_load(p, __ATOMIC_RELAXED, __HIP_MEMORY_SCOPE_AGENT);
}
__device__ __forceinline__ void astore(ull* p, ull v) {
  __hip_atomic_store(p, v, __ATOMIC_RELAXED, __HIP_MEMORY_SCOPE_AGENT);
}
__device__ __forceinline__ void fstore(ull* p, ull v) {   // plain store -> lands in XCD L2
  __hip_atomic_store(p, v, __ATOMIC_RELAXED, __HIP_MEMORY_SCOPE_WORKGROUP);
}
__device__ __forceinline__ float lo32(ull v) {
  return __builtin_bit_cast(float, (unsigned)v);
}
// 4x 8B loads at SE scope (bypass L1, read XCD L2)
__device__ __forceinline__ void fload4(const ull* p, ull& a0, ull& a1, ull& a2, ull& a3) {
  asm volatile("global_load_dwordx2 %0, %4, off sc0\n\t"
               "global_load_dwordx2 %1, %4, off offset:8 sc0\n\t"
               "global_load_dwordx2 %2, %4, off offset:16 sc0\n\t"
               "global_load_dwordx2 %3, %4, off offset:24 sc0\n\t"
               "s_waitcnt vmcnt(0)"
               : "=&v"(a0), "=&v"(a1), "=&v"(a2), "=&v"(a3)
               : "v"(p) : "memory");
}
__device__ __forceinline__ unsigned tagbad4(ull a0, ull a1, ull a2, ull a3, unsigned tg) {
  return ((unsigned)(a0 >> 32) ^ tg) | ((unsigned)(a1 >> 32) ^ tg) |
         ((unsigned)(a2 >> 32) ^ tg) | ((unsigned)(a3 >> 32) ^ tg);
}
// fast poll with periodic slow fallback
__device__ __forceinline__ f32x4 poll4_fs(const ull* fp, const ull* sp, unsigned tg) {
  ull a0, a1, a2, a3; int it = 0;
  for (;;) {
    fload4(fp, a0, a1, a2, a3);
    if (!tagbad4(a0, a1, a2, a3, tg)) break;
    if ((it & 7) == 7) {
      ull c0 = aload(sp), c1 = aload(sp + 1), c2 = aload(sp + 2), c3 = aload(sp + 3);
      if (!tagbad4(c0, c1, c2, c3, tg)) { a0 = c0; a1 = c1; a2 = c2; a3 = c3; break; }
    }
    ++it; __builtin_amdgcn_s_sleep(1);
  }
  f32x4 v; v.x = lo32(a0); v.y = lo32(a1); v.z = lo32(a2); v.w = lo32(a3); return v;
}
// slow-only poll (cross-XCD rings)
__device__ __forceinline__ f32x4 poll4_s(const ull* sp, unsigned tg) {
  ull a0, a1, a2, a3;
  for (;;) {
    a0 = aload(sp); a1 = aload(sp + 1); a2 = aload(sp + 2); a3 = aload(sp + 3);
    if (!tagbad4(a0, a1, a2, a3, tg)) break;
    __builtin_amdgcn_s_sleep(2);
  }
  f32x4 v; v.x = lo32(a0); v.y = lo32(a1); v.z = lo32(a2); v.w = lo32(a3); return v;
}

__global__ void init_kernel() {
  int t = threadIdx.x;   // 1024 threads
  g_h1f[t] = 0; g_rh1f[t] = 0; g_rh1R[t] = 0;
  g_h2f[t] = 0; g_h2R[t] = 0; g_rh2f[t] = 0; g_rh2R[t] = 0;
  if (t < 4) g_claim[t] = 0;
}

// ---------------- fused 3-cohort persistent GRU pipeline ----------------
// role 0 (L1, XCD0-preferred): recurrent layer 1, fast-path hops, publishes h1 ring.
// role 1 (L2, XCD1-preferred): recurrent layer 2 (U-mats only), fast-path hops,
//   consumes x2 rings, writes hs2.
// role 2 (proj, anywhere): feed-forward x2 = W*2^T . h1(s), ring->ring, latency-tolerant.
// All roles: 64 WGs x 256 thr; wave = 4 cols x 16 slices-of-64; 192 weight f/thread.
__global__ __launch_bounds__(256, 1) void fused_scan(
    const float* __restrict__ ExW,
    const float* __restrict__ Uz1, const float* __restrict__ Ur1,
    const float* __restrict__ Uw1, const float* __restrict__ bU1,
    const float* __restrict__ Wz2, const float* __restrict__ Wr2,
    const float* __restrict__ Ww2,
    const float* __restrict__ Uz2, const float* __restrict__ Ur2,
    const float* __restrict__ Uw2,
    const float* __restrict__ bW2, const float* __restrict__ bU2,
    float* __restrict__ hs2)
{
  __shared__ int sh_role, sh_rank;
  const int tid = threadIdx.x;
  if (tid == 0) {
    int xcd = __builtin_amdgcn_s_getreg(HWREG_XCC_ID) & 7;
    int pref = (xcd == 0) ? 0 : ((xcd == 1) ? 1 : 2);
    int role = -1, rk = 0;
    int s0 = atomicAdd(&g_claim[pref], 1);
    if (s0 < 64) { role = pref; rk = s0; }
    else if (blockIdx.x >= 768) {          // late sweep: guarantee all roles fill
      for (int r = 0; r < 3 && role < 0; ++r) {
        int s2 = atomicAdd(&g_claim[r], 1);
        if (s2 < 64) { role = r; rk = s2; }
      }
    }
    sh_role = role; sh_rank = rk;
  }
  __syncthreads();
  const int role = sh_role, g = sh_rank;
  if (role < 0) return;

  const int wv = tid >> 6, inw = tid & 63;
  const int c2 = inw >> 4, q = inw & 15;
  const int j = g * 16 + wv * 4 + c2;
  __shared__ __align__(16) float h_s[1088];
  __shared__ __align__(16) float rh_s[1088];

  if (role == 0) {
    // ================= layer 1 =================
    float uz[64], ur[64], uw[64];
#pragma unroll
    for (int i = 0; i < 64; ++i) uz[i] = Uz1[(size_t)(q * 64 + i) * 1024 + j];
#pragma unroll
    for (int i = 0; i < 64; ++i) ur[i] = Ur1[(size_t)(q * 64 + i) * 1024 + j];
#pragma unroll
    for (int i = 0; i < 64; ++i) uw[i] = Uw1[(size_t)(q * 64 + i) * 1024 + j];
#pragma unroll
    for (int i = 0; i < 64; ++i) { KEEPF(uz[i]); KEEPF(ur[i]); KEEPF(uw[i]); }
    const float bu = bU1[j];

    float xz = 0.f, xr = 0.f, xw = 0.f;
    if (q == 0) { xz = ExW[j]; xr = ExW[1024 + j]; xw = ExW[2048 + j]; }

    float zreg = 0.f, hold = 0.f;
    for (int s = 0; s < 1024; ++s) {
      f32x4 hv4 = poll4_fs(g_h1f + tid * 4, g_h1s + (size_t)s * 1024 + tid * 4, (unsigned)s);
      *(f32x4*)&h_s[PHYS(tid * 4)] = hv4;
      __syncthreads();   // A
      if (q == 0) hold = h_s[PHYS(j)];
      float ar_ = 0.f;
      {
        const float* hp = h_s + q * 68;
#pragma unroll
        for (int i2 = 0; i2 < 16; ++i2) {
          f32x4 hv = *(const f32x4*)(hp + i2 * 4);
          ar_ = fmaf(ur[i2 * 4 + 0], hv.x, ar_); ar_ = fmaf(ur[i2 * 4 + 1], hv.y, ar_);
          ar_ = fmaf(ur[i2 * 4 + 2], hv.z, ar_); ar_ = fmaf(ur[i2 * 4 + 3], hv.w, ar_);
        }
      }
      ar_ += __shfl_xor(ar_, 1, 64); ar_ += __shfl_xor(ar_, 2, 64);
      ar_ += __shfl_xor(ar_, 4, 64); ar_ += __shfl_xor(ar_, 8, 64);
      if (q == 0) {
        float r = 1.f / (1.f + __expf(-(ar_ + xr)));
        ull pk = packtv((unsigned)(s + 1), r * hold);
        fstore(&g_rh1f[j], pk);
        astore(&g_rh1R[j], pk);
      }
      // z-dot + ExW prefetch inside the rh wait window
      float az_ = 0.f;
      {
        const float* hp = h_s + q * 68;
#pragma unroll
        for (int i2 = 0; i2 < 16; ++i2) {
          f32x4 hv = *(const f32x4*)(hp + i2 * 4);
          az_ = fmaf(uz[i2 * 4 + 0], hv.x, az_); az_ = fmaf(uz[i2 * 4 + 1], hv.y, az_);
          az_ = fmaf(uz[i2 * 4 + 2], hv.z, az_); az_ = fmaf(uz[i2 * 4 + 3], hv.w, az_);
        }
      }
      az_ += __shfl_xor(az_, 1, 64); az_ += __shfl_xor(az_, 2, 64);
      az_ += __shfl_xor(az_, 4, 64); az_ += __shfl_xor(az_, 8, 64);
      if (q == 0) zreg = 1.f / (1.f + __expf(-(az_ + xz)));
      float nxz = 0.f, nxr = 0.f, nxw = 0.f;
      if (q == 0 && s < 1023) {
        nxz = ExW[(s + 1) * 3072 + j];
        nxr = ExW[(s + 1) * 3072 + 1024 + j];
        nxw = ExW[(s + 1) * 3072 + 2048 + j];
      }
      f32x4 rv4 = poll4_fs(g_rh1f + tid * 4, g_rh1R + tid * 4, (unsigned)(s + 1));
      *(f32x4*)&rh_s[PHYS(tid * 4)] = rv4;
      __syncthreads();   // B
      float aw_ = 0.f;
      {
        const float* rp = rh_s + q * 68;
#pragma unroll
        for (int i2 = 0; i2 < 16; ++i2) {
          f32x4 rv = *(const f32x4*)(rp + i2 * 4);
          aw_ = fmaf(uw[i2 * 4 + 0], rv.x, aw_); aw_ = fmaf(uw[i2 * 4 + 1], rv.y, aw_);
          aw_ = fmaf(uw[i2 * 4 + 2], rv.z, aw_); aw_ = fmaf(uw[i2 * 4 + 3], rv.w, aw_);
        }
      }
      aw_ += __shfl_xor(aw_, 1, 64); aw_ += __shfl_xor(aw_, 2, 64);
      aw_ += __shfl_xor(aw_, 4, 64); aw_ += __shfl_xor(aw_, 8, 64);
      if (q == 0) {
        float ht = tanhf(aw_ + xw + bu);
        float hn = zreg * ht + (1.f - zreg) * hold;
        ull pk = packtv((unsigned)(s + 1), hn);
        fstore(&g_h1f[j], pk);                          // fast (XCD0 L2)
        astore(&g_h1s[(size_t)(s + 1) * 1024 + j], pk); // ring (slow; proj + fallback)
      }
      xz = nxz; xr = nxr; xw = nxw;
    }
  } else if (role == 1) {
    // ================= layer 2 (U-mats only; x2 from proj rings) =================
    float uz[64], ur[64], uw[64];
#pragma unroll
    for (int i = 0; i < 64; ++i) uz[i] = Uz2[(size_t)(q * 64 + i) * 1024 + j];
#pragma unroll
    for (int i = 0; i < 64; ++i) ur[i] = Ur2[(size_t)(q * 64 + i) * 1024 + j];
#pragma unroll
    for (int i = 0; i < 64; ++i) uw[i] = Uw2[(size_t)(q * 64 + i) * 1024 + j];
#pragma unroll
    for (int i = 0; i < 64; ++i) { KEEPF(uz[i]); KEEPF(ur[i]); KEEPF(uw[i]); }
    const float bu = bW2[j] + bU2[j];

    float zreg = 0.f, hold = 0.f;
    for (int s = 0; s < 1024; ++s) {
      // joint poll: h2 (fast+slow fb) for own 4 cols; q==0 lanes also x2 rings (slow)
      float xz = 0.f, xr = 0.f, xw = 0.f;
      {
        const ull* fp = g_h2f + tid * 4;
        const ull* sp = g_h2R + tid * 4;
        const ull* pz = g_x2z + (size_t)(s + 1) * 1024 + j;
        const ull* pr = g_x2r + (size_t)(s + 1) * 1024 + j;
        const ull* pw = g_x2w + (size_t)(s + 1) * 1024 + j;
        const unsigned tgh = (unsigned)s, tgx = (unsigned)(s + 1);
        ull a0, a1, a2, a3, b0 = 0, b1 = 0, b2 = 0;
        bool hok = false, xok = (q != 0);
        int it = 0;
        for (;;) {
          if (!hok) {
            fload4(fp, a0, a1, a2, a3);
            if (!tagbad4(a0, a1, a2, a3, tgh)) hok = true;
            else if ((it & 7) == 7) {
              ull c0 = aload(sp), c1 = aload(sp + 1), c2_ = aload(sp + 2), c3 = aload(sp + 3);
              if (!tagbad4(c0, c1, c2_, c3, tgh)) { a0 = c0; a1 = c1; a2 = c2_; a3 = c3; hok = true; }
            }
          }
          if (!xok) {
            b0 = aload(pz); b1 = aload(pr); b2 = aload(pw);
            unsigned xb = ((unsigned)(b0 >> 32) ^ tgx) | ((unsigned)(b1 >> 32) ^ tgx) |
                          ((unsigned)(b2 >> 32) ^ tgx);
            if (!xb) xok = true;
          }
          if (hok && xok) break;
          ++it; __builtin_amdgcn_s_sleep(1);
        }
        if (q == 0) { xz = lo32(b0); xr = lo32(b1); xw = lo32(b2); }
        f32x4 v; v.x = lo32(a0); v.y = lo32(a1); v.z = lo32(a2); v.w = lo32(a3);
        *(f32x4*)&h_s[PHYS(tid * 4)] = v;
      }
      __syncthreads();   // A
      if (q == 0) hold = h_s[PHYS(j)];
      float ar_ = 0.f;
      {
        const float* hp = h_s + q * 68;
#pragma unroll
        for (int i2 = 0; i2 < 16; ++i2) {
          f32x4 hv = *(const f32x4*)(hp + i2 * 4);
          ar_ = fmaf(ur[i2 * 4 + 0], hv.x, ar_); ar_ = fmaf(ur[i2 * 4 + 1], hv.y, ar_);
          ar_ = fmaf(ur[i2 * 4 + 2], hv.z, ar_); ar_ = fmaf(ur[i2 * 4 + 3], hv.w, ar_);
        }
      }
      ar_ += __shfl_xor(ar_, 1, 64); ar_ += __shfl_xor(ar_, 2, 64);
      ar_ += __shfl_xor(ar_, 4, 64); ar_ += __shfl_xor(ar_, 8, 64);
      if (q == 0) {
        float r = 1.f / (1.f + __expf(-(ar_ + xr)));
        ull pk = packtv((unsigned)(s + 1), r * hold);
        fstore(&g_rh2f[j], pk);
        astore(&g_rh2R[j], pk);
      }
      float az_ = 0.f;
      {
        const float* hp = h_s + q * 68;
#pragma unroll
        for (int i2 = 0; i2 < 16; ++i2) {
          f32x4 hv = *(const f32x4*)(hp + i2 * 4);
          az_ = fmaf(uz[i2 * 4 + 0], hv.x, az_); az_ = fmaf(uz[i2 * 4 + 1], hv.y, az_);
          az_ = fmaf(uz[i2 * 4 + 2], hv.z, az_); az_ = fmaf(uz[i2 * 4 + 3], hv.w, az_);
        }
      }
      az_ += __shfl_xor(az_, 1, 64); az_ += __shfl_xor(az_, 2, 64);
      az_ += __shfl_xor(az_, 4, 64); az_ += __shfl_xor(az_, 8, 64);
      if (q == 0) zreg = 1.f / (1.f + __expf(-(az_ + xz)));
      f32x4 rv4 = poll4_fs(g_rh2f + tid * 4, g_rh2R + tid * 4, (unsigned)(s + 1));
      *(f32x4*)&rh_s[PHYS(tid * 4)] = rv4;
      __syncthreads();   // B
      float aw_ = 0.f;
      {
        const float* rp = rh_s + q * 68;
#pragma unroll
        for (int i2 = 0; i2 < 16; ++i2) {
          f32x4 rv = *(const f32x4*)(rp + i2 * 4);
          aw_ = fmaf(uw[i2 * 4 + 0], rv.x, aw_); aw_ = fmaf(uw[i2 * 4 + 1], rv.y, aw_);
          aw_ = fmaf(uw[i2 * 4 + 2], rv.z, aw_); aw_ = fmaf(uw[i2 * 4 + 3], rv.w, aw_);
        }
      }
      aw_ += __shfl_xor(aw_, 1, 64); aw_ += __shfl_xor(aw_, 2, 64);
      aw_ += __shfl_xor(aw_, 4, 64); aw_ += __shfl_xor(aw_, 8, 64);
      if (q == 0) {
        float ht = tanhf(aw_ + xw + bu);
        float hn = zreg * ht + (1.f - zreg) * hold;
        hs2[(size_t)s * 1024 + j] = hn;
        ull pk = packtv((unsigned)(s + 1), hn);
        fstore(&g_h2f[j], pk);
        astore(&g_h2R[j], pk);
      }
    }
  } else {
    // ================= proj: x2 = W*2^T . h1(s) (feed-forward, ring->ring) =========
    float wz[64], wr[64], ww[64];
#pragma unroll
    for (int i = 0; i < 64; ++i) wz[i] = Wz2[(size_t)(q * 64 + i) * 1024 + j];
#pragma unroll
    for (int i = 0; i < 64; ++i) wr[i] = Wr2[(size_t)(q * 64 + i) * 1024 + j];
#pragma unroll
    for (int i = 0; i < 64; ++i) ww[i] = Ww2[(size_t)(q * 64 + i) * 1024 + j];
#pragma unroll
    for (int i = 0; i < 64; ++i) { KEEPF(wz[i]); KEEPF(wr[i]); KEEPF(ww[i]); }

    for (int s = 0; s < 1024; ++s) {
      f32x4 v = poll4_s(g_h1s + (size_t)(s + 1) * 1024 + tid * 4, (unsigned)(s + 1));
      *(f32x4*)&h_s[PHYS(tid * 4)] = v;
      __syncthreads();   // A
      float az_ = 0.f, ar_ = 0.f, aw_ = 0.f;
      {
        const float* hp = h_s + q * 68;
#pragma unroll
        for (int i2 = 0; i2 < 16; ++i2) {
          f32x4 hv = *(const f32x4*)(hp + i2 * 4);
          az_ = fmaf(wz[i2 * 4 + 0], hv.x, az_); az_ = fmaf(wz[i2 * 4 + 1], hv.y, az_);
          az_ = fmaf(wz[i2 * 4 + 2], hv.z, az_); az_ = fmaf(wz[i2 * 4 + 3], hv.w, az_);
          ar_ = fmaf(wr[i2 * 4 + 0], hv.x, ar_); ar_ = fmaf(wr[i2 * 4 + 1], hv.y, ar_);
          ar_ = fmaf(wr[i2 * 4 + 2], hv.z, ar_); ar_ = fmaf(wr[i2 * 4 + 3], hv.w, ar_);
          aw_ = fmaf(ww[i2 * 4 + 0], hv.x, aw_); aw_ = fmaf(ww[i2 * 4 + 1], hv.y, aw_);
          aw_ = fmaf(ww[i2 * 4 + 2], hv.z, aw_); aw_ = fmaf(ww[i2 * 4 + 3], hv.w, aw_);
        }
      }
      az_ += __shfl_xor(az_, 1, 64); az_ += __shfl_xor(az_, 2, 64);
      az_ += __shfl_xor(az_, 4, 64); az_ += __shfl_xor(az_, 8, 64);
      ar_ += __shfl_xor(ar_, 1, 64); ar_ += __shfl_xor(ar_, 2, 64);
      ar_ += __shfl_xor(ar_, 4, 64); ar_ += __shfl_xor(ar_, 8, 64);
      aw_ += __shfl_xor(aw_, 1, 64); aw_ += __shfl_xor(aw_, 2, 64);
      aw_ += __shfl_xor(aw_, 4, 64); aw_ += __shfl_xor(aw_, 8, 64);
      if (q == 0) {
        const unsigned tg = (unsigned)(s + 1);
        astore(&g_x2z[(size_t)(s + 1) * 1024 + j], packtv(tg, az_));
        astore(&g_x2r[(size_t)(s + 1) * 1024 + j], packtv(tg, ar_));
        astore(&g_x2w[(size_t)(s + 1) * 1024 + j], packtv(tg, aw_));
      }
      __syncthreads();   // B: protect h_s before next overwrite
    }
  }
}

// ---------------- bf16 MFMA GEMM: C[M=1024][N] = A(f32,[gather])*B(f32) + bias ----------------
__global__ __launch_bounds__(256, 1) void gemm_mfma(
    const float* __restrict__ A, const int* __restrict__ gidx, int lda,
    const float* __restrict__ B, int ldb,
    const float* __restrict__ bias,
    float* __restrict__ C, int ldc, int N, int K)
{
  __shared__ unsigned short As[128 * GPAD];
  __shared__ unsigned short Bs[128 * GPAD];
  const int tid = threadIdx.x;
  const int lane = tid & 63;
  const int wv = tid >> 6;
  const int wm = wv >> 1, wn = wv & 1;
  const int mbase = blockIdx.y * 128, nbase = blockIdx.x * 128;

  f32x4 acc[4][4];
#pragma unroll
  for (int i = 0; i < 4; ++i)
#pragma unroll
    for (int qq = 0; qq < 4; ++qq) acc[i][qq] = (f32x4){0.f, 0.f, 0.f, 0.f};

  const int ar = tid >> 1, ak = (tid & 1) * 16;
  const float* Arow;
  {
    int m = mbase + ar;
    long long gr = gidx ? (long long)gidx[m] : (long long)m;
    Arow = A + (size_t)gr * (size_t)lda;
  }
  const int bn = (tid >> 3) * 4;
  const int bk = (tid & 7) * 4;
  const bool nedge = (nbase + 128 > N);

  const int ksteps = (K + 31) >> 5;
  for (int ks = 0; ks < ksteps; ++ks) {
    const int k0 = ks << 5;
    __syncthreads();
    {
      float v[16];
      const int kg = k0 + ak;
      if (kg + 16 <= K) {
#pragma unroll
        for (int qq = 0; qq < 4; ++qq) {
          f32x4 t = *(const f32x4*)(Arow + kg + qq * 4);
          v[qq * 4 + 0] = t.x; v[qq * 4 + 1] = t.y; v[qq * 4 + 2] = t.z; v[qq * 4 + 3] = t.w;
        }
      } else {
#pragma unroll
        for (int i = 0; i < 16; ++i) v[i] = (kg + i < K) ? Arow[kg + i] : 0.f;
      }
#pragma unroll
      for (int qq = 0; qq < 4; ++qq) {
        u16x4 wq;
        wq.x = f2bf(v[qq * 4 + 0]); wq.y = f2bf(v[qq * 4 + 1]);
        wq.z = f2bf(v[qq * 4 + 2]); wq.w = f2bf(v[qq * 4 + 3]);
        *(u16x4*)&As[ar * GPAD + ak + qq * 4] = wq;
      }
    }
    {
      float bv[4][4];
#pragma unroll
      for (int kk = 0; kk < 4; ++kk) {
        int kglob = k0 + bk + kk;
        if (kglob < K) {
          if (!nedge) {
            f32x4 t = *(const f32x4*)(B + (size_t)kglob * (size_t)ldb + nbase + bn);
            bv[kk][0] = t.x; bv[kk][1] = t.y; bv[kk][2] = t.z; bv[kk][3] = t.w;
          } else {
#pragma unroll
            for (int nn = 0; nn < 4; ++nn) {
              int n = nbase + bn + nn;
              bv[kk][nn] = (n < N) ? B[(size_t)kglob * (size_t)ldb + n] : 0.f;
            }
          }
        } else {
          bv[kk][0] = bv[kk][1] = bv[kk][2] = bv[kk][3] = 0.f;
        }
      }
#pragma unroll
      for (int nn = 0; nn < 4; ++nn) {
        u16x4 wq;
        wq.x = f2bf(bv[0][nn]); wq.y = f2bf(bv[1][nn]);
        wq.z = f2bf(bv[2][nn]); wq.w = f2bf(bv[3][nn]);
        *(u16x4*)&Bs[(bn + nn) * GPAD + bk] = wq;
      }
    }
    __syncthreads();
    bf16x8 af[4], bfr[4];
    const int fr = lane & 15, fk = (lane >> 4) * 8;
#pragma unroll
    for (int mf = 0; mf < 4; ++mf)
      af[mf] = *(const bf16x8*)&As[(wm * 64 + mf * 16 + fr) * GPAD + fk];
#pragma unroll
    for (int nf = 0; nf < 4; ++nf)
      bfr[nf] = *(const bf16x8*)&Bs[(wn * 64 + nf * 16 + fr) * GPAD + fk];
#pragma unroll
    for (int mf = 0; mf < 4; ++mf)
#pragma unroll
      for (int nf = 0; nf < 4; ++nf)
        acc[mf][nf] = __builtin_amdgcn_mfma_f32_16x16x32_bf16(af[mf], bfr[nf], acc[mf][nf], 0, 0, 0);
  }
  const int fr = lane & 15, fq = lane >> 4;
#pragma unroll
  for (int nf = 0; nf < 4; ++nf) {
    int col = nbase + wn * 64 + nf * 16 + fr;
    if (col < N) {
      float bb = bias ? bias[col] : 0.f;
#pragma unroll
      for (int mf = 0; mf < 4; ++mf) {
        int row0 = mbase + wm * 64 + mf * 16 + fq * 4;
#pragma unroll
        for (int r = 0; r < 4; ++r)
          C[(size_t)(row0 + r) * (size_t)ldc + col] = acc[mf][nf][r] + bb;
      }
    }
  }
}

// ---------------- row-wise log-softmax, in place on d_out ----------------
__global__ __launch_bounds__(256, 1) void logsoftmax_kernel(float* __restrict__ out) {
  const int row = blockIdx.x;
  float* p; int len;
  if (row < 1024) { p = out + (size_t)row * 50000u; len = 50000; }
  else            { p = out + 51200000ull + (size_t)(row - 1024) * 25000u; len = 25000; }
  const int tid = threadIdx.x;
  __shared__ float mred[4], sred[4];

  float m = -3.4e38f;
  for (int i = tid * 4; i < len; i += 1024) {
    f32x4 v = *(const f32x4*)(p + i);
    m = fmaxf(m, fmaxf(fmaxf(v.x, v.y), fmaxf(v.z, v.w)));
  }
#pragma unroll
  for (int off = 32; off >= 1; off >>= 1) m = fmaxf(m, __shfl_xor(m, off, 64));
  if ((tid & 63) == 0) mred[tid >> 6] = m;
  __syncthreads();
  m = fmaxf(fmaxf(mred[0], mred[1]), fmaxf(mred[2], mred[3]));

  float ssum = 0.f;
  for (int i = tid * 4; i < len; i += 1024) {
    f32x4 v = *(const f32x4*)(p + i);
    ssum += __expf(v.x - m) + __expf(v.y - m) + __expf(v.z - m) + __expf(v.w - m);
  }
#pragma unroll
  for (int off = 32; off >= 1; off >>= 1) ssum += __shfl_xor(ssum, off, 64);
  if ((tid & 63) == 0) sred[tid >> 6] = ssum;
  __syncthreads();
  const float lse = m + logf(sred[0] + sred[1] + sred[2] + sred[3]);

  for (int i = tid * 4; i < len; i += 1024) {
    f32x4 v = *(const f32x4*)(p + i);
    v.x -= lse; v.y -= lse; v.z -= lse; v.w -= lse;
    *(f32x4*)(p + i) = v;
  }
}

// ---------------- launch ----------------
extern "C" void kernel_launch(void* const* d_in, const int* in_sizes, int n_in,
                              void* d_out, int out_size, void* d_ws, size_t ws_size,
                              hipStream_t stream) {
  (void)in_sizes; (void)n_in; (void)out_size; (void)d_ws; (void)ws_size;
  const int*   x_idx = (const int*)  d_in[0];
  const float* X     = (const float*)d_in[1];
  const float* W_z_1 = (const float*)d_in[2];
  const float* U_z_1 = (const float*)d_in[3];
  const float* W_r_1 = (const float*)d_in[4];
  const float* U_r_1 = (const float*)d_in[5];
  const float* W_1   = (const float*)d_in[6];
  const float* b_W_1 = (const float*)d_in[7];
  const float* U_1   = (const float*)d_in[8];
  const float* b_U_1 = (const float*)d_in[9];
  const float* W_z_2 = (const float*)d_in[10];
  const float* U_z_2 = (const float*)d_in[11];
  const float* W_r_2 = (const float*)d_in[12];
  const float* U_r_2 = (const float*)d_in[13];
  const float* W_2   = (const float*)d_in[14];
  const float* b_W_2 = (const float*)d_in[15];
  const float* U_2   = (const float*)d_in[16];
  const float* b_U_2 = (const float*)d_in[17];
  const float* W_g   = (const float*)d_in[18];
  const float* b_g   = (const float*)d_in[19];
  const float* W_s   = (const float*)d_in[20];
  const float* b_s   = (const float*)d_in[21];
  float* out = (float*)d_out;

  float *ExW, *hs2;
  ull *h1s, *x2z, *x2r, *x2w;
  hipGetSymbolAddress((void**)&ExW, HIP_SYMBOL(g_ExW));
  hipGetSymbolAddress((void**)&hs2, HIP_SYMBOL(g_hs2));
  hipGetSymbolAddress((void**)&h1s, HIP_SYMBOL(g_h1s));
  hipGetSymbolAddress((void**)&x2z, HIP_SYMBOL(g_x2z));
  hipGetSymbolAddress((void**)&x2r, HIP_SYMBOL(g_x2r));
  hipGetSymbolAddress((void**)&x2w, HIP_SYMBOL(g_x2w));

  const dim3 blk(256);

  // reset sync state: rings (stale tags would match) + fast/slow singles + claims
  hipMemsetAsync(h1s, 0, 1025ull * 1024 * sizeof(ull), stream);
  hipMemsetAsync(x2z, 0, 1025ull * 1024 * sizeof(ull), stream);
  hipMemsetAsync(x2r, 0, 1025ull * 1024 * sizeof(ull), stream);
  hipMemsetAsync(x2w, 0, 1025ull * 1024 * sizeof(ull), stream);
  init_kernel<<<dim3(1), dim3(1024), 0, stream>>>();

  // layer-1 input projections: E(=X[idx]) @ {W_z_1, W_r_1, W_1}  -> g_ExW
  gemm_mfma<<<dim3(8, 8), blk, 0, stream>>>(X, x_idx, 300, W_z_1, 1024, nullptr, ExW + 0,    3072, 1024, 300);
  gemm_mfma<<<dim3(8, 8), blk, 0, stream>>>(X, x_idx, 300, W_r_1, 1024, nullptr, ExW + 1024, 3072, 1024, 300);
  gemm_mfma<<<dim3(8, 8), blk, 0, stream>>>(X, x_idx, 300, W_1,   1024, b_W_1,   ExW + 2048, 3072, 1024, 300);

  // fused 3-cohort pipeline: L1 (XCD0) + L2 (XCD1) + proj, self-organized by XCC_ID
  fused_scan<<<dim3(1280), blk, 0, stream>>>(
      ExW, U_z_1, U_r_1, U_1, b_U_1,
      W_z_2, W_r_2, W_2, U_z_2, U_r_2, U_2, b_W_2, b_U_2, hs2);

  // heads: logits straight into d_out
  gemm_mfma<<<dim3(391, 8), blk, 0, stream>>>(hs2, nullptr, 1024, W_g, 50000, b_g, out,              50000, 50000, 1024);
  gemm_mfma<<<dim3(196, 8), blk, 0, stream>>>(hs2, nullptr, 1024, W_s, 25000, b_s, out + 51200000ll, 25000, 25000, 1024);
  // in-place log-softmax
  logsoftmax_kernel<<<dim3(2048), blk, 0, stream>>>(out);
}